// Round 1
// baseline (2327.558 us; speedup 1.0000x reference)
//
#include <hip/hip_runtime.h>
#include <stdint.h>

// HeteroscedasticSoftmax: out = mean_{s<100} softmax(logits + eps_s * exp(log_std), axis=C)
// eps_s reproduces jax.random.normal(split(key(1),100)[s], [8,19,256,256]) bit-exactly
// under the *partitionable* threefry scheme (modern JAX default):
//   key_s  = threefry2x32((0,1), (0, s))            -> (w0, w1)
//   bits_j = w0 ^ w1 of threefry2x32(key_s, (0, j)) -> j = flat index
//   u      = bitcast((bits>>9)|0x3F800000)-1, u = u*2 + nextafter(-1,0), clamp
//   eps    = sqrt(2) * erfinv(u)   (XLA/Giles f32 polynomial)

#define NCH    19
#define HW     65536
#define NSAMP  100

__device__ __forceinline__ uint32_t rotl32(uint32_t x, uint32_t r) {
  return (x << r) | (x >> (32u - r));
}

__device__ __forceinline__ void tf2x32(uint32_t k0, uint32_t k1,
                                       uint32_t x0, uint32_t x1,
                                       uint32_t& o0, uint32_t& o1) {
  const uint32_t k2 = k0 ^ k1 ^ 0x1BD11BDAu;
#define TFRND(r) { x0 += x1; x1 = rotl32(x1, r); x1 ^= x0; }
  x0 += k0; x1 += k1;
  TFRND(13u) TFRND(15u) TFRND(26u) TFRND(6u)
  x0 += k1; x1 += k2 + 1u;
  TFRND(17u) TFRND(29u) TFRND(16u) TFRND(24u)
  x0 += k2; x1 += k0 + 2u;
  TFRND(13u) TFRND(15u) TFRND(26u) TFRND(6u)
  x0 += k0; x1 += k1 + 3u;
  TFRND(17u) TFRND(29u) TFRND(16u) TFRND(24u)
  x0 += k1; x1 += k2 + 4u;
  TFRND(13u) TFRND(15u) TFRND(26u) TFRND(6u)
  x0 += k2; x1 += k0 + 5u;
#undef TFRND
  o0 = x0; o1 = x1;
}

__device__ __forceinline__ float bits_to_eps(uint32_t bits) {
  const float lo = -0.99999994f;  // nextafter(-1, 0) in f32
  float f = __uint_as_float((bits >> 9) | 0x3F800000u) - 1.0f;  // [0, 1)
  float u = fmaf(f, 2.0f, lo);    // (maxval-minval) rounds to exactly 2.0f
  u = fmaxf(u, lo);
  // sqrt(2) * erfinv(u), XLA f32 polynomial (Giles)
  float w = -__logf(fmaf(-u, u, 1.0f));
  float p;
  if (w < 5.0f) {
    w -= 2.5f;
    p = 2.81022636e-08f;
    p = fmaf(p, w, 3.43273939e-07f);
    p = fmaf(p, w, -3.5233877e-06f);
    p = fmaf(p, w, -4.39150654e-06f);
    p = fmaf(p, w, 0.00021858087f);
    p = fmaf(p, w, -0.00125372503f);
    p = fmaf(p, w, -0.00417768164f);
    p = fmaf(p, w, 0.246640727f);
    p = fmaf(p, w, 1.50140941f);
  } else {
    w = __fsqrt_rn(w) - 3.0f;
    p = -0.000200214257f;
    p = fmaf(p, w, 0.000100950558f);
    p = fmaf(p, w, 0.00134934322f);
    p = fmaf(p, w, -0.00367342844f);
    p = fmaf(p, w, 0.00573950773f);
    p = fmaf(p, w, -0.0076224613f);
    p = fmaf(p, w, 0.00943887047f);
    p = fmaf(p, w, 1.00167406f);
    p = fmaf(p, w, 2.83297682f);
  }
  return 1.41421356237f * (p * u);
}

__global__ __launch_bounds__(256, 2)
void HeteroscedasticSoftmax_kernel(const float* __restrict__ in,
                                   float* __restrict__ out) {
  __shared__ uint32_t sk0[NSAMP];
  __shared__ uint32_t sk1[NSAMP];
  const int t = threadIdx.x;
  if (t < NSAMP) {
    uint32_t a, b;
    tf2x32(0u, 1u, 0u, (uint32_t)t, a, b);  // fold-like split of key(1)
    sk0[t] = a;
    sk1[t] = b;
  }
  __syncthreads();

  const int gid = blockIdx.x * 256 + t;  // [0, 8*256*256)
  const int b_  = gid >> 16;             // batch 0..7
  const int hw  = gid & 65535;           // h*256+w

  // input layout [8, 38, 256, 256]: channels 0..18 logits, 19..37 log_std
  const float* pin = in + (size_t)b_ * (2 * NCH * HW) + hw;
  float lg[NCH], sd[NCH], acc[NCH];
#pragma unroll
  for (int c = 0; c < NCH; ++c) {
    lg[c]  = pin[c * HW];
    sd[c]  = __expf(pin[(NCH + c) * HW]);
    acc[c] = 0.0f;
  }

  const uint32_t jbase = (uint32_t)(b_ * NCH) * (uint32_t)HW + (uint32_t)hw;

#pragma unroll 1
  for (int s = 0; s < NSAMP; ++s) {
    const uint32_t k0 = sk0[s], k1 = sk1[s];
    float z[NCH];
    float m = -1e30f;
#pragma unroll
    for (int c = 0; c < NCH; ++c) {
      uint32_t o0, o1;
      tf2x32(k0, k1, 0u, jbase + (uint32_t)c * HW, o0, o1);
      const float eps = bits_to_eps(o0 ^ o1);
      z[c] = fmaf(eps, sd[c], lg[c]);
      m = fmaxf(m, z[c]);
    }
    float ssum = 0.0f;
#pragma unroll
    for (int c = 0; c < NCH; ++c) {
      z[c] = __expf(z[c] - m);
      ssum += z[c];
    }
    const float r = 1.0f / ssum;  // ssum >= 1 always (max channel contributes exp(0))
#pragma unroll
    for (int c = 0; c < NCH; ++c) acc[c] = fmaf(z[c], r, acc[c]);
  }

  float* pout = out + (size_t)b_ * (NCH * HW) + hw;
#pragma unroll
  for (int c = 0; c < NCH; ++c) pout[c * HW] = acc[c] * 0.01f;
}

extern "C" void kernel_launch(void* const* d_in, const int* in_sizes, int n_in,
                              void* d_out, int out_size, void* d_ws, size_t ws_size,
                              hipStream_t stream) {
  const float* in = (const float*)d_in[0];
  float* out = (float*)d_out;
  // 8*256*256 pixels, one thread each -> 2048 blocks x 256 threads (exact cover)
  HeteroscedasticSoftmax_kernel<<<2048, 256, 0, stream>>>(in, out);
}

// Round 2
// 2271.799 us; speedup vs baseline: 1.0245x; 1.0245x over previous
//
#include <hip/hip_runtime.h>
#include <stdint.h>

// HeteroscedasticSoftmax: out = mean_{s<100} softmax(logits + eps_s * exp(log_std), axis=C)
// eps reproduces jax.random.normal under the partitionable threefry scheme (verified R0):
//   key_s  = threefry2x32((0,1), (0, s))
//   bits_j = w0 ^ w1 of threefry2x32(key_s, (0, j)), j = flat element index
//   u = bitcast((bits>>9)|0x3F800000)-1; u = u*2 + nextafter(-1,0); clamp; eps = sqrt2*erfinv(u)
//
// R1 changes (VALU-issue-bound; cut instruction count + dependency latency):
//  - explicit v_alignbit_b32 rotates (3 ops/round guaranteed)
//  - key injections folded into following round add (v_add3_u32), keys in SGPRs
//  - sqrt(2) folded into erfinv polynomial coefficients
//  - logits/std pre-scaled by log2(e) -> raw v_exp_f32 in softmax (no per-exp mul)
//  - pairwise-tree max/sum reductions (depth 19 -> 5)
//  - v_rcp_f32 for 1/sum

#define NCH    19
#define HW     65536
#define NSAMP  100

__device__ __forceinline__ uint32_t rotl(uint32_t x, uint32_t r) {
  return __builtin_amdgcn_alignbit(x, x, 32u - r);  // rotr by 32-r == rotl by r
}

// Full 20-round threefry2x32 used once per sample-key setup (generic x0,x1).
__device__ __forceinline__ void tf2x32_full(uint32_t k0, uint32_t k1,
                                            uint32_t x0, uint32_t x1,
                                            uint32_t& o0, uint32_t& o1) {
  const uint32_t k2 = k0 ^ k1 ^ 0x1BD11BDAu;
#define TFR(r) { x0 += x1; x1 = rotl(x1, r) ^ x0; }
  x0 += k0; x1 += k1;
  TFR(13u) TFR(15u) TFR(26u) TFR(6u)
  x0 += k1; x1 += k2 + 1u;
  TFR(17u) TFR(29u) TFR(16u) TFR(24u)
  x0 += k2; x1 += k0 + 2u;
  TFR(13u) TFR(15u) TFR(26u) TFR(6u)
  x0 += k0; x1 += k1 + 3u;
  TFR(17u) TFR(29u) TFR(16u) TFR(24u)
  x0 += k1; x1 += k2 + 4u;
  TFR(13u) TFR(15u) TFR(26u) TFR(6u)
  x0 += k2; x1 += k0 + 5u;
#undef TFR
  o0 = x0; o1 = x1;
}

// Hot-path threefry with x0_in = 0, returning the folded output o0^o1.
// Key material (k0,k1,k2 and the +c constants) is wave-uniform (SGPR).
__device__ __forceinline__ uint32_t tf_fold(uint32_t k0, uint32_t k1, uint32_t k2,
                                            uint32_t x1in) {
  uint32_t x0, x1;
  x1 = x1in + k1;            // initial injection on x1; x0 = 0 + k0 handled below
  x0 = k0 + x1;              // round 1 add folds initial x0 injection
  x1 = rotl(x1, 13u) ^ x0;
  x0 += x1; x1 = rotl(x1, 15u) ^ x0;
  x0 += x1; x1 = rotl(x1, 26u) ^ x0;
  x0 += x1; x1 = rotl(x1,  6u) ^ x0;
  // inject (k1, k2+1), fold x0-part into round-5 add (v_add3)
  x1 += k2 + 1u;
  x0 = x0 + k1 + x1; x1 = rotl(x1, 17u) ^ x0;
  x0 += x1; x1 = rotl(x1, 29u) ^ x0;
  x0 += x1; x1 = rotl(x1, 16u) ^ x0;
  x0 += x1; x1 = rotl(x1, 24u) ^ x0;
  x1 += k0 + 2u;
  x0 = x0 + k2 + x1; x1 = rotl(x1, 13u) ^ x0;
  x0 += x1; x1 = rotl(x1, 15u) ^ x0;
  x0 += x1; x1 = rotl(x1, 26u) ^ x0;
  x0 += x1; x1 = rotl(x1,  6u) ^ x0;
  x1 += k1 + 3u;
  x0 = x0 + k0 + x1; x1 = rotl(x1, 17u) ^ x0;
  x0 += x1; x1 = rotl(x1, 29u) ^ x0;
  x0 += x1; x1 = rotl(x1, 16u) ^ x0;
  x0 += x1; x1 = rotl(x1, 24u) ^ x0;
  x1 += k2 + 4u;
  x0 = x0 + k1 + x1; x1 = rotl(x1, 13u) ^ x0;
  x0 += x1; x1 = rotl(x1, 15u) ^ x0;
  x0 += x1; x1 = rotl(x1, 26u) ^ x0;
  x0 += x1; x1 = rotl(x1,  6u) ^ x0;
  // final injection + fold
  return (x0 + k2) ^ (x1 + k0 + 5u);
}

// sqrt(2)*erfinv(u) with sqrt(2) pre-folded into the polynomial coefficients.
__device__ __forceinline__ float bits_to_eps(uint32_t bits) {
  const float lo = -0.99999994f;  // nextafter(-1, 0)
  float f = __uint_as_float((bits >> 9) | 0x3F800000u) - 1.0f;  // [0,1)
  float u = fmaf(f, 2.0f, lo);
  u = fmaxf(u, lo);
  float w = -__logf(fmaf(-u, u, 1.0f));
  float p;
  if (w < 5.0f) {
    w -= 2.5f;
    p = 3.9742683e-08f;
    p = fmaf(p, w, 4.8546493e-07f);
    p = fmaf(p, w, -4.9828230e-06f);
    p = fmaf(p, w, -6.2105302e-06f);
    p = fmaf(p, w, 3.0912002e-04f);
    p = fmaf(p, w, -1.7730354e-03f);
    p = fmaf(p, w, -5.9081371e-03f);
    p = fmaf(p, w, 3.4880267e-01f);
    p = fmaf(p, w, 2.1233141e+00f);
  } else {
    w = __fsqrt_rn(w) - 3.0f;
    p = -2.8314594e-04f;
    p = fmaf(p, w, 1.4276565e-04f);
    p = fmaf(p, w, 1.9082604e-03f);
    p = fmaf(p, w, -5.1950124e-03f);
    p = fmaf(p, w, 8.1168916e-03f);
    p = fmaf(p, w, -1.0779791e-02f);
    p = fmaf(p, w, 1.3348577e-02f);
    p = fmaf(p, w, 1.4165810e+00f);
    p = fmaf(p, w, 4.0064324e+00f);
  }
  return p * u;
}

__global__ __launch_bounds__(256, 2)
void HeteroscedasticSoftmax_kernel(const float* __restrict__ in,
                                   float* __restrict__ out) {
  __shared__ uint32_t sk0[NSAMP];
  __shared__ uint32_t sk1[NSAMP];
  const int t = threadIdx.x;
  if (t < NSAMP) {
    uint32_t a, b;
    tf2x32_full(0u, 1u, 0u, (uint32_t)t, a, b);  // split of key(1)
    sk0[t] = a;
    sk1[t] = b;
  }
  __syncthreads();

  const int gid = blockIdx.x * 256 + t;  // [0, 8*256*256)
  const int b_  = gid >> 16;
  const int hw  = gid & 65535;

  const float L2E = 1.4426950408889634f;  // log2(e)
  const float* pin = in + (size_t)b_ * (2 * NCH * HW) + hw;
  float lgl[NCH], sdl[NCH], acc[NCH];
#pragma unroll
  for (int c = 0; c < NCH; ++c) {
    lgl[c] = pin[c * HW] * L2E;                      // logits * log2(e)
    sdl[c] = __expf(pin[(NCH + c) * HW]) * L2E;      // std * log2(e)
    acc[c] = 0.0f;
  }

  const uint32_t jbase = (uint32_t)(b_ * NCH) * (uint32_t)HW + (uint32_t)hw;

#pragma unroll 1
  for (int s = 0; s < NSAMP; ++s) {
    const uint32_t k0 = __builtin_amdgcn_readfirstlane(sk0[s]);
    const uint32_t k1 = __builtin_amdgcn_readfirstlane(sk1[s]);
    const uint32_t k2 = k0 ^ k1 ^ 0x1BD11BDAu;

    float z[NCH];
#pragma unroll
    for (int c = 0; c < NCH; ++c) {
      const uint32_t bits = tf_fold(k0, k1, k2, jbase + (uint32_t)c * HW);
      const float eps = bits_to_eps(bits);
      z[c] = fmaf(eps, sdl[c], lgl[c]);  // (lg + eps*sd) * log2(e)
    }

    // pairwise-tree max over 19 (depth 5)
    float m0 = fmaxf(z[0], z[1]),  m1 = fmaxf(z[2], z[3]);
    float m2 = fmaxf(z[4], z[5]),  m3 = fmaxf(z[6], z[7]);
    float m4 = fmaxf(z[8], z[9]),  m5 = fmaxf(z[10], z[11]);
    float m6 = fmaxf(z[12], z[13]), m7 = fmaxf(z[14], z[15]);
    float m8 = fmaxf(z[16], z[17]);
    m0 = fmaxf(m0, m1); m2 = fmaxf(m2, m3); m4 = fmaxf(m4, m5);
    m6 = fmaxf(m6, m7); m8 = fmaxf(m8, z[18]);
    m0 = fmaxf(m0, m2); m4 = fmaxf(m4, m6);
    m0 = fmaxf(m0, m4);
    const float m = fmaxf(m0, m8);

#pragma unroll
    for (int c = 0; c < NCH; ++c) z[c] = __builtin_amdgcn_exp2f(z[c] - m);

    // pairwise-tree sum (depth 5)
    float s0 = z[0] + z[1],  s1 = z[2] + z[3];
    float s2 = z[4] + z[5],  s3 = z[6] + z[7];
    float s4 = z[8] + z[9],  s5 = z[10] + z[11];
    float s6 = z[12] + z[13], s7 = z[14] + z[15];
    float s8 = z[16] + z[17];
    s0 += s1; s2 += s3; s4 += s5; s6 += s7; s8 += z[18];
    s0 += s2; s4 += s6;
    s0 += s4;
    const float r = __builtin_amdgcn_rcpf(s0 + s8);

#pragma unroll
    for (int c = 0; c < NCH; ++c) acc[c] = fmaf(z[c], r, acc[c]);
  }

  float* pout = out + (size_t)b_ * (NCH * HW) + hw;
#pragma unroll
  for (int c = 0; c < NCH; ++c) pout[c * HW] = acc[c] * 0.01f;
}

extern "C" void kernel_launch(void* const* d_in, const int* in_sizes, int n_in,
                              void* d_out, int out_size, void* d_ws, size_t ws_size,
                              hipStream_t stream) {
  const float* in = (const float*)d_in[0];
  float* out = (float*)d_out;
  HeteroscedasticSoftmax_kernel<<<2048, 256, 0, stream>>>(in, out);
}

// Round 3
// 2119.496 us; speedup vs baseline: 1.0982x; 1.0719x over previous
//
#include <hip/hip_runtime.h>
#include <stdint.h>

// HeteroscedasticSoftmax: out = mean_{s<100} softmax(logits + eps_s * exp(log_std), axis=C)
// eps reproduces jax.random.normal under the partitionable threefry scheme (verified R0/R1):
//   key_s  = threefry2x32((0,1), (0, s))
//   bits_j = w0 ^ w1 of threefry2x32(key_s, (0, j)), j = flat element index
//   u = bitcast((bits>>9)|0x3F800000) scaled; eps = sqrt2*erfinv(u) (coeff-folded)
//
// R2: occupancy attack (R1 showed 39% occupancy, ~150 regs/wave incl AGPR spills):
//  - lgl/sdl (38 floats) staged in LDS as float2, ds_read_b64 per channel-sample
//    (LDS pipe co-issues with VALU; 2-way bank aliasing is free)
//  - __launch_bounds__(256,4): force <=128 regs -> 4 waves/SIMD
//  - erfinv central poly refit in t = log2(1-u^2) domain (folds the -ln2 mul);
//    sqrt(2) still folded in; tail branch recomputes w = -ln2*t (rare)

#define NCH    19
#define HW     65536
#define NSAMP  100

__device__ __forceinline__ uint32_t rotl(uint32_t x, uint32_t r) {
  return __builtin_amdgcn_alignbit(x, x, 32u - r);
}

__device__ __forceinline__ void tf2x32_full(uint32_t k0, uint32_t k1,
                                            uint32_t x0, uint32_t x1,
                                            uint32_t& o0, uint32_t& o1) {
  const uint32_t k2 = k0 ^ k1 ^ 0x1BD11BDAu;
#define TFR(r) { x0 += x1; x1 = rotl(x1, r) ^ x0; }
  x0 += k0; x1 += k1;
  TFR(13u) TFR(15u) TFR(26u) TFR(6u)
  x0 += k1; x1 += k2 + 1u;
  TFR(17u) TFR(29u) TFR(16u) TFR(24u)
  x0 += k2; x1 += k0 + 2u;
  TFR(13u) TFR(15u) TFR(26u) TFR(6u)
  x0 += k0; x1 += k1 + 3u;
  TFR(17u) TFR(29u) TFR(16u) TFR(24u)
  x0 += k1; x1 += k2 + 4u;
  TFR(13u) TFR(15u) TFR(26u) TFR(6u)
  x0 += k2; x1 += k0 + 5u;
#undef TFR
  o0 = x0; o1 = x1;
}

// Hot-path threefry, x0_in = 0, returns o0^o1. Keys wave-uniform (SGPR).
__device__ __forceinline__ uint32_t tf_fold(uint32_t k0, uint32_t k1, uint32_t k2,
                                            uint32_t x1in) {
  uint32_t x0, x1;
  x1 = x1in + k1;
  x0 = k0 + x1;
  x1 = rotl(x1, 13u) ^ x0;
  x0 += x1; x1 = rotl(x1, 15u) ^ x0;
  x0 += x1; x1 = rotl(x1, 26u) ^ x0;
  x0 += x1; x1 = rotl(x1,  6u) ^ x0;
  x1 += k2 + 1u;
  x0 = x0 + k1 + x1; x1 = rotl(x1, 17u) ^ x0;
  x0 += x1; x1 = rotl(x1, 29u) ^ x0;
  x0 += x1; x1 = rotl(x1, 16u) ^ x0;
  x0 += x1; x1 = rotl(x1, 24u) ^ x0;
  x1 += k0 + 2u;
  x0 = x0 + k2 + x1; x1 = rotl(x1, 13u) ^ x0;
  x0 += x1; x1 = rotl(x1, 15u) ^ x0;
  x0 += x1; x1 = rotl(x1, 26u) ^ x0;
  x0 += x1; x1 = rotl(x1,  6u) ^ x0;
  x1 += k1 + 3u;
  x0 = x0 + k0 + x1; x1 = rotl(x1, 17u) ^ x0;
  x0 += x1; x1 = rotl(x1, 29u) ^ x0;
  x0 += x1; x1 = rotl(x1, 16u) ^ x0;
  x0 += x1; x1 = rotl(x1, 24u) ^ x0;
  x1 += k2 + 4u;
  x0 = x0 + k1 + x1; x1 = rotl(x1, 13u) ^ x0;
  x0 += x1; x1 = rotl(x1, 15u) ^ x0;
  x0 += x1; x1 = rotl(x1, 26u) ^ x0;
  x0 += x1; x1 = rotl(x1,  6u) ^ x0;
  return (x0 + k2) ^ (x1 + k0 + 5u);
}

// sqrt(2)*erfinv(u); central poly evaluated directly in t = log2(1-u^2)
// (alpha = -ln2 folded into coefficients; center beta = 2.5/alpha).
__device__ __forceinline__ float bits_to_eps(uint32_t bits) {
  const float lo = -0.99999994f;  // nextafter(-1, 0)
  // x = bitcast((bits>>9)|0x3F800000) in [1,2); u = 2x - 2 + lo
  float x = __uint_as_float((bits >> 9) | 0x3F800000u);
  float u = fmaf(x, 2.0f, -2.99999994f);
  u = fmaxf(u, lo);
  float t = __builtin_amdgcn_logf(fmaf(-u, u, 1.0f));  // log2(1-u^2), <= 0
  float p;
  if (t > -7.2135401f) {          // w = -ln2*t < 5  (central branch)
    float tw = t + 3.6067376f;    // t - beta
    p = 2.1176667e-09f;
    p = fmaf(p, tw, -3.7319753e-08f);
    p = fmaf(p, tw, -5.5262077e-07f);
    p = fmaf(p, tw, 9.9370361e-07f);
    p = fmaf(p, tw, 7.1355918e-05f);
    p = fmaf(p, tw, 5.9046852e-04f);
    p = fmaf(p, tw, -2.8386612e-03f);
    p = fmaf(p, tw, -2.4177230e-01f);
    p = fmaf(p, tw, 2.1233141e+00f);
  } else {                        // tail (rare): reconstruct w
    float w = -0.69314718f * t;
    w = __fsqrt_rn(w) - 3.0f;
    p = -2.8314594e-04f;
    p = fmaf(p, w, 1.4276565e-04f);
    p = fmaf(p, w, 1.9082604e-03f);
    p = fmaf(p, w, -5.1950124e-03f);
    p = fmaf(p, w, 8.1168916e-03f);
    p = fmaf(p, w, -1.0779791e-02f);
    p = fmaf(p, w, 1.3348577e-02f);
    p = fmaf(p, w, 1.4165810e+00f);
    p = fmaf(p, w, 4.0064324e+00f);
  }
  return p * u;
}

__global__ __launch_bounds__(256, 4)
void HeteroscedasticSoftmax_kernel(const float* __restrict__ in,
                                   float* __restrict__ out) {
  __shared__ float2 sls[NCH][256];   // (logit*log2e, std*log2e) per channel x thread
  __shared__ uint2  skey[NSAMP];

  const int t = threadIdx.x;
  if (t < NSAMP) {
    uint32_t a, b;
    tf2x32_full(0u, 1u, 0u, (uint32_t)t, a, b);
    skey[t] = make_uint2(a, b);
  }

  const int gid = blockIdx.x * 256 + t;
  const int b_  = gid >> 16;
  const int hw  = gid & 65535;

  const float L2E = 1.4426950408889634f;
  const float* pin = in + (size_t)b_ * (2 * NCH * HW) + hw;
  float acc[NCH];
#pragma unroll
  for (int c = 0; c < NCH; ++c) {
    float lg = pin[c * HW];
    float ls = pin[(NCH + c) * HW];
    sls[c][t] = make_float2(lg * L2E, __expf(ls) * L2E);
    acc[c] = 0.0f;
  }
  __syncthreads();

  const uint32_t jbase = (uint32_t)(b_ * NCH) * (uint32_t)HW + (uint32_t)hw;

#pragma unroll 1
  for (int s = 0; s < NSAMP; ++s) {
    const uint2 kk = skey[s];
    const uint32_t k0 = __builtin_amdgcn_readfirstlane(kk.x);
    const uint32_t k1 = __builtin_amdgcn_readfirstlane(kk.y);
    const uint32_t k2 = k0 ^ k1 ^ 0x1BD11BDAu;

    float z[NCH];
#pragma unroll
    for (int c = 0; c < NCH; ++c) {
      const uint32_t bits = tf_fold(k0, k1, k2, jbase + (uint32_t)c * HW);
      const float eps = bits_to_eps(bits);
      const float2 ls = sls[c][t];
      z[c] = fmaf(eps, ls.y, ls.x);   // (lg + eps*sd) * log2(e)
    }

    float m0 = fmaxf(z[0], z[1]),  m1 = fmaxf(z[2], z[3]);
    float m2 = fmaxf(z[4], z[5]),  m3 = fmaxf(z[6], z[7]);
    float m4 = fmaxf(z[8], z[9]),  m5 = fmaxf(z[10], z[11]);
    float m6 = fmaxf(z[12], z[13]), m7 = fmaxf(z[14], z[15]);
    float m8 = fmaxf(z[16], z[17]);
    m0 = fmaxf(m0, m1); m2 = fmaxf(m2, m3); m4 = fmaxf(m4, m5);
    m6 = fmaxf(m6, m7); m8 = fmaxf(m8, z[18]);
    m0 = fmaxf(m0, m2); m4 = fmaxf(m4, m6);
    m0 = fmaxf(m0, m4);
    const float m = fmaxf(m0, m8);

#pragma unroll
    for (int c = 0; c < NCH; ++c) z[c] = __builtin_amdgcn_exp2f(z[c] - m);

    float s0 = z[0] + z[1],  s1 = z[2] + z[3];
    float s2 = z[4] + z[5],  s3 = z[6] + z[7];
    float s4 = z[8] + z[9],  s5 = z[10] + z[11];
    float s6 = z[12] + z[13], s7 = z[14] + z[15];
    float s8 = z[16] + z[17];
    s0 += s1; s2 += s3; s4 += s5; s6 += s7; s8 += z[18];
    s0 += s2; s4 += s6;
    s0 += s4;
    const float r = __builtin_amdgcn_rcpf(s0 + s8);

#pragma unroll
    for (int c = 0; c < NCH; ++c) acc[c] = fmaf(z[c], r, acc[c]);
  }

  float* pout = out + (size_t)b_ * (NCH * HW) + hw;
#pragma unroll
  for (int c = 0; c < NCH; ++c) pout[c * HW] = acc[c] * 0.01f;
}

extern "C" void kernel_launch(void* const* d_in, const int* in_sizes, int n_in,
                              void* d_out, int out_size, void* d_ws, size_t ws_size,
                              hipStream_t stream) {
  const float* in = (const float*)d_in[0];
  float* out = (float*)d_out;
  HeteroscedasticSoftmax_kernel<<<2048, 256, 0, stream>>>(in, out);
}